// Round 1
// baseline (1265.598 us; speedup 1.0000x reference)
//
#include <hip/hip_runtime.h>

#define Bk 16
#define Hk 256
#define Lk 8192
#define N2k 32
#define Tk 64            // chunk length
#define Gk (Lk / Tk)     // 128 chunks

// Workspace layout (bytes), total ~12.9 MB:
//   MD   (double[H*N2*4])   @ 0        : per-mode {dr, di, ctr, cti} in double
//   WS64 (float2[H*N2])     @ 262144   : w^64 (chunk-scan multiplier)
//   kvec (float[H*64])      @ 327680   : real conv kernel k[d], d<64 (k[0] += D)
//   Ptab (float[H*64*64])   @ 393216   : state-build table  P[m][j] = Re/Im(w^(63-j))
//   Ktab (float[H*64*64])   @ 4587520  : tri-Toeplitz intra-conv K[l][j] = k[l-j]
//   Etab (float[H*64*64])   @ 8781824  : carry table E[l][2n]=Re(ct*w^(l+1)), [2n+1]=-Im

// ---- precompute stage 0: per-mode constants (double) ----
__global__ void s4d_p0(const float* __restrict__ log_dt,
                       const float* __restrict__ log_A_real,
                       const float* __restrict__ A_imag,
                       const float* __restrict__ C,
                       double* __restrict__ MD,
                       float2* __restrict__ WS64) {
    int t = blockIdx.x * blockDim.x + threadIdx.x;
    if (t >= Hk * N2k) return;
    int h = t >> 5;
    double dt  = exp((double)log_dt[h]);
    double are = -exp((double)log_A_real[t]);
    double aim = (double)A_imag[t];
    double dr = dt * are, di = dt * aim;
    double er = exp(dr);
    double wre = er * cos(di), wim = er * sin(di);
    double denom = are * are + aim * aim;
    double tr = wre - 1.0, ti = wim;
    double qr = (tr * are + ti * aim) / denom;   // (w-1)/A
    double qi = (ti * are - tr * aim) / denom;
    double c0 = (double)C[2 * t], c1 = (double)C[2 * t + 1];
    double ctr = 2.0 * (c0 * qr - c1 * qi);
    double cti = 2.0 * (c0 * qi + c1 * qr);
    MD[4 * t] = dr; MD[4 * t + 1] = di; MD[4 * t + 2] = ctr; MD[4 * t + 3] = cti;
    double esr = exp((double)Tk * dr), ang = (double)Tk * di;
    WS64[t] = make_float2((float)(esr * cos(ang)), (float)(esr * sin(ang)));
}

// ---- precompute P: row m (=2n+comp) over j: w_n^(63-j), iterative double powers ----
__global__ void s4d_p1(const double* __restrict__ MD, float* __restrict__ Ptab) {
    int t = blockIdx.x * blockDim.x + threadIdx.x; // (h, m) in [0, H*64)
    if (t >= Hk * 64) return;
    int h = t >> 6, m = t & 63, n = m >> 1;
    int idx = (h << 5) + n;
    double dr = MD[4 * idx], di = MD[4 * idx + 1];
    double er = exp(dr);
    double wre = er * cos(di), wim = er * sin(di);
    double cr = 1.0, ci = 0.0;
    float* row = Ptab + (size_t)t * 64;
    for (int p = 0; p < 64; ++p) {       // power p stored at j = 63-p
        row[63 - p] = (float)((m & 1) ? ci : cr);
        double nr = cr * wre - ci * wim;
        double nc = cr * wim + ci * wre;
        cr = nr; ci = nc;
    }
}

// ---- precompute kvec + Etab: thread per (h,l) ----
__global__ void s4d_p2(const double* __restrict__ MD, const float* __restrict__ Dv,
                       float* __restrict__ kvec, float* __restrict__ Etab) {
    int t = blockIdx.x * blockDim.x + threadIdx.x; // (h, l)
    if (t >= Hk * 64) return;
    int h = t >> 6, l = t & 63;
    double acc = 0.0;
    float* erow = Etab + (size_t)t * 64;
    for (int n = 0; n < N2k; ++n) {
        int idx = (h << 5) + n;
        double dr = MD[4 * idx], di = MD[4 * idx + 1];
        double ctr = MD[4 * idx + 2], cti = MD[4 * idx + 3];
        double e1 = exp((double)l * dr), a1 = (double)l * di;
        acc += ctr * (e1 * cos(a1)) - cti * (e1 * sin(a1));       // Re(ct * w^l)
        double e2 = exp((double)(l + 1) * dr), a2 = (double)(l + 1) * di;
        double re2 = e2 * cos(a2), im2 = e2 * sin(a2);            // w^(l+1)
        erow[2 * n]     = (float)(ctr * re2 - cti * im2);         //  Re(ct*w^(l+1))
        erow[2 * n + 1] = (float)(-(ctr * im2 + cti * re2));      // -Im(ct*w^(l+1))
    }
    if (l == 0) acc += (double)Dv[h];    // fold D*u into k[0]
    kvec[t] = (float)acc;
}

// ---- precompute Ktab: lower-tri Toeplitz from kvec ----
__global__ void s4d_p3(const float* __restrict__ kvec, float* __restrict__ Ktab) {
    int t = blockIdx.x * blockDim.x + threadIdx.x; // (h, l)
    if (t >= Hk * 64) return;
    int h = t >> 6, l = t & 63;
    const float* kv = kvec + (h << 6);
    float* row = Ktab + (size_t)t * 64;
    for (int j = 0; j < 64; ++j) row[j] = (j <= l) ? kv[l - j] : 0.f;
}

// ---- fused main kernel: one workgroup per (b,h) ----
// Phase 1: V[c][m] = sum_j P[m][j]*u[c*64+j]  (lane=m, u broadcast, P in regs)
// Phase 2: exclusive chunk scan with w^64 in LDS (wave 0, lanes 0..31)
// Phase 3: y[c*64+l] = sum_j K[l][j]*u[c*64+j] + sum_m E[l][m]*s0[c][m]
//          (lane=l, K/E rows in regs, u & s0 broadcast, coalesced store)
__global__ __launch_bounds__(256) void s4d_fused(
    const float* __restrict__ u,
    const float* __restrict__ Ptab,
    const float* __restrict__ Ktab,
    const float* __restrict__ Etab,
    const float2* __restrict__ WS64,
    float* __restrict__ y) {
    __shared__ float S[Gk * Tk];   // 32 KB: per-chunk states (raw V, then scanned s0)
    int bh = blockIdx.x;           // b*H + h
    int h = bh & (Hk - 1);
    int lane = threadIdx.x & 63;
    int wv = threadIdx.x >> 6;     // wave 0..3, owns columns [32*wv, 32*wv+32)
    const float* ub = u + (size_t)bh * Lk;

    // ---- phase 1 ----
    {
        float p[64];
        const float4* prow = (const float4*)(Ptab + (size_t)(((h << 6) + lane) << 6));
        #pragma unroll
        for (int i = 0; i < 16; ++i) {
            float4 v = prow[i];
            p[4 * i] = v.x; p[4 * i + 1] = v.y; p[4 * i + 2] = v.z; p[4 * i + 3] = v.w;
        }
        #pragma unroll 1
        for (int c = wv * 32; c < (wv + 1) * 32; ++c) {
            const float4* uc = (const float4*)(ub + (c << 6));
            float a0 = 0.f, a1 = 0.f, a2 = 0.f, a3 = 0.f;
            #pragma unroll
            for (int i = 0; i < 16; ++i) {
                float4 uv = uc[i];
                a0 = fmaf(p[4 * i],     uv.x, a0);
                a1 = fmaf(p[4 * i + 1], uv.y, a1);
                a2 = fmaf(p[4 * i + 2], uv.z, a2);
                a3 = fmaf(p[4 * i + 3], uv.w, a3);
            }
            S[(c << 6) + lane] = (a0 + a1) + (a2 + a3);  // 2-way bank alias = free
        }
    }
    __syncthreads();

    // ---- phase 2: exclusive scan over 128 chunks (serial, 1 wave; other wgs fill CU) ----
    if (threadIdx.x < 32) {
        int n = threadIdx.x;
        float2 ws = WS64[(h << 5) + n];
        float zr = 0.f, zi = 0.f;
        for (int c = 0; c < Gk; ++c) {
            float* s = S + (c << 6) + (n << 1);
            float vr = s[0], vi = s[1];
            s[0] = zr; s[1] = zi;                         // in-place: V -> s0 (exclusive)
            float zr2 = fmaf(ws.x, zr, fmaf(-ws.y, zi, vr));
            float zi2 = fmaf(ws.x, zi, fmaf( ws.y, zr, vi));
            zr = zr2; zi = zi2;
        }
    }
    __syncthreads();

    // ---- phase 3 ----
    float kr[64], er[64];
    {
        const float4* krow = (const float4*)(Ktab + (size_t)(((h << 6) + lane) << 6));
        const float4* erow = (const float4*)(Etab + (size_t)(((h << 6) + lane) << 6));
        #pragma unroll
        for (int i = 0; i < 16; ++i) {
            float4 a = krow[i];
            float4 b = erow[i];
            kr[4 * i] = a.x; kr[4 * i + 1] = a.y; kr[4 * i + 2] = a.z; kr[4 * i + 3] = a.w;
            er[4 * i] = b.x; er[4 * i + 1] = b.y; er[4 * i + 2] = b.z; er[4 * i + 3] = b.w;
        }
    }
    float* yb = y + (size_t)bh * Lk;
    #pragma unroll 1
    for (int c = wv * 32; c < (wv + 1) * 32; ++c) {
        const float4* uc = (const float4*)(ub + (c << 6));
        const float4* sc = (const float4*)(S + (c << 6));  // broadcast reads
        float a0 = 0.f, a1 = 0.f, a2 = 0.f, a3 = 0.f;
        #pragma unroll
        for (int i = 0; i < 16; ++i) {
            float4 uv = uc[i];
            a0 = fmaf(kr[4 * i],     uv.x, a0);
            a1 = fmaf(kr[4 * i + 1], uv.y, a1);
            a2 = fmaf(kr[4 * i + 2], uv.z, a2);
            a3 = fmaf(kr[4 * i + 3], uv.w, a3);
        }
        #pragma unroll
        for (int i = 0; i < 16; ++i) {
            float4 sv = sc[i];
            a0 = fmaf(er[4 * i],     sv.x, a0);
            a1 = fmaf(er[4 * i + 1], sv.y, a1);
            a2 = fmaf(er[4 * i + 2], sv.z, a2);
            a3 = fmaf(er[4 * i + 3], sv.w, a3);
        }
        yb[(c << 6) + lane] = (a0 + a1) + (a2 + a3);       // coalesced 256B store
    }
}

extern "C" void kernel_launch(void* const* d_in, const int* in_sizes, int n_in,
                              void* d_out, int out_size, void* d_ws, size_t ws_size,
                              hipStream_t stream) {
    const float* u          = (const float*)d_in[0];
    const float* log_dt     = (const float*)d_in[1];
    const float* log_A_real = (const float*)d_in[2];
    const float* A_imag     = (const float*)d_in[3];
    const float* C          = (const float*)d_in[4];
    const float* D          = (const float*)d_in[5];
    float* y = (float*)d_out;

    char* ws = (char*)d_ws;
    double* MD   = (double*)(ws);
    float2* WS64 = (float2*)(ws + 262144);
    float*  kvec = (float*) (ws + 327680);
    float*  Ptab = (float*) (ws + 393216);
    float*  Ktab = (float*) (ws + 4587520);
    float*  Etab = (float*) (ws + 8781824);

    s4d_p0<<<(Hk * N2k) / 256, 256, 0, stream>>>(log_dt, log_A_real, A_imag, C, MD, WS64);
    s4d_p1<<<(Hk * 64) / 256, 256, 0, stream>>>(MD, Ptab);
    s4d_p2<<<(Hk * 64) / 256, 256, 0, stream>>>(MD, D, kvec, Etab);
    s4d_p3<<<(Hk * 64) / 256, 256, 0, stream>>>(kvec, Ktab);
    s4d_fused<<<Bk * Hk, 256, 0, stream>>>(u, Ptab, Ktab, Etab, WS64, y);
}

// Round 3
// 697.081 us; speedup vs baseline: 1.8156x; 1.8156x over previous
//
#include <hip/hip_runtime.h>

#define Bk 16
#define Hk 256
#define Lk 8192
#define N2k 32
#define Tk 64            // chunk length
#define Gk 128           // chunks per (b,h)
#define NSEG 8           // scan segments
#define SEGC 16          // chunks per segment

typedef __attribute__((ext_vector_type(8))) short short8;
typedef __attribute__((ext_vector_type(4))) float f32x4;

__device__ __forceinline__ f32x4 mfma16(short8 a, short8 b, f32x4 c) {
    return __builtin_amdgcn_mfma_f32_16x16x32_bf16(a, b, c, 0, 0, 0);
}

__device__ __forceinline__ void split1(float x, short& hi, short& lo) {
    __bf16 h = (__bf16)x;
    __bf16 l = (__bf16)(x - (float)h);
    hi = __builtin_bit_cast(short, h);
    lo = __builtin_bit_cast(short, l);
}

// short index inside the packed fragment tables for (h, col, k):
//   frag8 index = (((h*4 + col/16)*2 + k/32)*64 + ((k>>3)&3)*16 + (col&15)), elem = k&7
__device__ __forceinline__ int frag_sidx(int h, int col, int k) {
    int mt = col >> 4, kh = k >> 5;
    int lane = (((k >> 3) & 3) << 4) | (col & 15);
    return ((((((h << 2) + mt) << 1) + kh) << 6) + lane) * 8 + (k & 7);
}

// Workspace layout (bytes), ~12.9 MB total:
//   MD     double[H*N2*4]  @ 0        {dr, di, ctr, cti}
//   WS64   float2[H*N2]    @ 262144   w^64
//   WS1024 float2[H*N2]    @ 327680   w^1024
//   kvecd  double[H*64]    @ 393216   conv kernel k[d] (k[0] += D)
//   Phi    short[H*64*64]  @ 524288
//   Plo    short[H*64*64]  @ 2621440
//   Khi    short[H*64*64]  @ 4718592
//   Klo    short[H*64*64]  @ 6815744
//   Ef     float[H*64*64]  @ 8912896  Ef[(h*64+l)*64 + m], m=2n:Re(ct*w^(l+1)), 2n+1:-Im

__global__ void s4d_p0(const float* __restrict__ log_dt,
                       const float* __restrict__ log_A_real,
                       const float* __restrict__ A_imag,
                       const float* __restrict__ C,
                       double* __restrict__ MD,
                       float2* __restrict__ WS64,
                       float2* __restrict__ WS1024) {
    int t = blockIdx.x * blockDim.x + threadIdx.x;
    if (t >= Hk * N2k) return;
    int h = t >> 5;
    double dt  = exp((double)log_dt[h]);
    double are = -exp((double)log_A_real[t]);
    double aim = (double)A_imag[t];
    double dr = dt * are, di = dt * aim;
    double er = exp(dr);
    double wre = er * cos(di), wim = er * sin(di);
    double denom = are * are + aim * aim;
    double tr = wre - 1.0, ti = wim;
    double qr = (tr * are + ti * aim) / denom;   // (w-1)/A
    double qi = (ti * are - tr * aim) / denom;
    double c0 = (double)C[2 * t], c1 = (double)C[2 * t + 1];
    double ctr = 2.0 * (c0 * qr - c1 * qi);
    double cti = 2.0 * (c0 * qi + c1 * qr);
    MD[4 * t] = dr; MD[4 * t + 1] = di; MD[4 * t + 2] = ctr; MD[4 * t + 3] = cti;
    double e64 = exp(64.0 * dr), a64 = 64.0 * di;
    WS64[t] = make_float2((float)(e64 * cos(a64)), (float)(e64 * sin(a64)));
    double eS = exp(1024.0 * dr), aS = 1024.0 * di;
    WS1024[t] = make_float2((float)(eS * cos(aS)), (float)(eS * sin(aS)));
}

__global__ void s4d_pk(const double* __restrict__ MD, const float* __restrict__ Dv,
                       double* __restrict__ kvecd) {
    int t = blockIdx.x * blockDim.x + threadIdx.x; // (h, d)
    if (t >= Hk * 64) return;
    int h = t >> 6, d = t & 63;
    double acc = 0.0;
    for (int n = 0; n < N2k; ++n) {
        const double* md = MD + 4 * ((h << 5) + n);
        double e = exp((double)d * md[0]), a = (double)d * md[1];
        acc += md[2] * (e * cos(a)) - md[3] * (e * sin(a));
    }
    if (d == 0) acc += (double)Dv[h];
    kvecd[t] = acc;
}

// P table via recurrence: thread per (h, m); P[col=m][k] = Re/Im(w^(63-k))
__global__ void s4d_pp(const double* __restrict__ MD,
                       short* __restrict__ Phi, short* __restrict__ Plo) {
    int t = blockIdx.x * blockDim.x + threadIdx.x;
    if (t >= Hk * 64) return;
    int h = t >> 6, m = t & 63, n = m >> 1;
    const double* md = MD + 4 * ((h << 5) + n);
    double er = exp(md[0]);
    double wre = er * cos(md[1]), wim = er * sin(md[1]);
    double cr = 1.0, ci = 0.0;                    // w^0
    for (int p = 0; p < 64; ++p) {                // power p at k = 63-p
        float val = (float)((m & 1) ? ci : cr);
        short hi, lo; split1(val, hi, lo);
        int si = frag_sidx(h, m, 63 - p);
        Phi[si] = hi; Plo[si] = lo;
        double nr = cr * wre - ci * wim;
        double nc = cr * wim + ci * wre;
        cr = nr; ci = nc;
    }
}

// K table: thread per (h, col); K[col][k] = kvec[col-k] (0 if k > col)
__global__ void s4d_pkk(const double* __restrict__ kvecd,
                        short* __restrict__ Khi, short* __restrict__ Klo) {
    int t = blockIdx.x * blockDim.x + threadIdx.x;
    if (t >= Hk * 64) return;
    int h = t >> 6, col = t & 63;
    for (int k = 0; k < 64; ++k) {
        float val = (k <= col) ? (float)kvecd[(h << 6) + col - k] : 0.f;
        short hi, lo; split1(val, hi, lo);
        int si = frag_sidx(h, col, k);
        Khi[si] = hi; Klo[si] = lo;
    }
}

// Ef via recurrence: thread per (h, n); cur = ct*w^(l+1)
__global__ void s4d_pe(const double* __restrict__ MD, float* __restrict__ Ef) {
    int t = blockIdx.x * blockDim.x + threadIdx.x;
    if (t >= Hk * N2k) return;
    int h = t >> 5, n = t & 31;
    const double* md = MD + 4 * t;
    double er = exp(md[0]);
    double wre = er * cos(md[1]), wim = er * sin(md[1]);
    double cr = md[2] * wre - md[3] * wim;        // ct * w^1
    double ci = md[2] * wim + md[3] * wre;
    for (int l = 0; l < 64; ++l) {
        float* row = Ef + (((size_t)(h << 6) + l) << 6);
        row[2 * n]     = (float)cr;
        row[2 * n + 1] = (float)(-ci);
        double nr = cr * wre - ci * wim;
        double nc = cr * wim + ci * wre;
        cr = nr; ci = nc;
    }
}

// Fused main kernel: one wg (4 waves) per (b,h); wave wv owns chunks [32wv, 32wv+32).
// Phase 1 (MFMA): V^T = U^T * P^T  -> LDS S (LINEAR [c][m])
// Phase 2: segmented exclusive chunk scan (fp32)
// Carry (fp32 VALU): S[c][l] <- sum_m s0[c][m] * Ef[h][l][m]  (readlane broadcast)
// Phase 3 (MFMA): y = U^T * K^T + carry
__global__ __launch_bounds__(256) void s4d_mm2(
    const float* __restrict__ u,
    const short8* __restrict__ Phi, const short8* __restrict__ Plo,
    const short8* __restrict__ Khi, const short8* __restrict__ Klo,
    const float* __restrict__ Ef,
    const float2* __restrict__ WS64, const float2* __restrict__ WS1024,
    float* __restrict__ y) {
    __shared__ __align__(16) float S[Gk * Tk];   // 32 KB
    __shared__ float Lb[NSEG * 64];              // 2 KB

    int b = blockIdx.x & (Bk - 1);
    int h = blockIdx.x >> 4;
    int bh = b * Hk + h;
    int tid = threadIdx.x;
    int lane = tid & 63, wv = tid >> 6;
    int lr = lane & 15, lq = lane >> 4;
    int cbase = wv * 32;
    const float* ub = u + (size_t)bh * Lk;

    // ---- U fragments: row c = cbase+ct*16+lr, k j = kh*32+lq*8+e
    short8 Uhi[2][2], Ulo[2][2];
    #pragma unroll
    for (int ct = 0; ct < 2; ++ct)
        #pragma unroll
        for (int kh = 0; kh < 2; ++kh) {
            const float* src = ub + (size_t)(cbase + ct * 16 + lr) * 64 + kh * 32 + lq * 8;
            float4 a4 = *(const float4*)src;
            float4 c4 = *(const float4*)(src + 4);
            float v[8] = {a4.x, a4.y, a4.z, a4.w, c4.x, c4.y, c4.z, c4.w};
            #pragma unroll
            for (int e = 0; e < 8; ++e) {
                short hi, lo; split1(v[e], hi, lo);
                Uhi[ct][kh][e] = hi; Ulo[ct][kh][e] = lo;
            }
        }

    // ---- phase 1: V -> S (linear) ----
    #pragma unroll
    for (int mt = 0; mt < 4; ++mt) {
        int tb = (((h << 2) + mt) << 1) * 64 + lane;
        short8 Bh0 = Phi[tb], Bl0 = Plo[tb];
        short8 Bh1 = Phi[tb + 64], Bl1 = Plo[tb + 64];
        #pragma unroll
        for (int ct = 0; ct < 2; ++ct) {
            f32x4 a = {0.f, 0.f, 0.f, 0.f};
            a = mfma16(Uhi[ct][0], Bh0, a);
            a = mfma16(Ulo[ct][0], Bh0, a);
            a = mfma16(Uhi[ct][0], Bl0, a);
            a = mfma16(Uhi[ct][1], Bh1, a);
            a = mfma16(Ulo[ct][1], Bh1, a);
            a = mfma16(Uhi[ct][1], Bl1, a);
            #pragma unroll
            for (int r = 0; r < 4; ++r)
                S[(cbase + ct * 16 + lq * 4 + r) * 64 + mt * 16 + lr] = a[r];
        }
    }

    // ---- E-row load (overlaps scan latency): lane l = lane ----
    float ef[64];
    {
        const float4* er4 = (const float4*)(Ef + (((size_t)(h << 6) + lane) << 6));
        #pragma unroll
        for (int i = 0; i < 16; ++i) {
            float4 e4 = er4[i];
            ef[4 * i] = e4.x; ef[4 * i + 1] = e4.y; ef[4 * i + 2] = e4.z; ef[4 * i + 3] = e4.w;
        }
    }
    __syncthreads();

    // ---- phase 2: segmented exclusive scan, thread = (mode n, segment g) ----
    {
        int n = tid & 31, g = tid >> 5;
        float2 W = WS64[(h << 5) + n];
        float zr = 0.f, zi = 0.f;
        for (int c = g * SEGC; c < g * SEGC + SEGC; ++c) {
            int a0 = c * 64 + 2 * n, a1 = a0 + 1;
            float vr = S[a0], vi = S[a1];
            S[a0] = zr; S[a1] = zi;
            float t_r = fmaf(W.x, zr, fmaf(-W.y, zi, vr));
            float t_i = fmaf(W.x, zi, fmaf(W.y, zr, vi));
            zr = t_r; zi = t_i;
        }
        Lb[g * 64 + 2 * n] = zr; Lb[g * 64 + 2 * n + 1] = zi;
        __syncthreads();
        if (tid < 32) {
            float2 Wseg = WS1024[(h << 5) + tid];
            float Zr = 0.f, Zi = 0.f;
            for (int g2 = 0; g2 < NSEG; ++g2) {
                float lr_ = Lb[g2 * 64 + 2 * tid], li_ = Lb[g2 * 64 + 2 * tid + 1];
                Lb[g2 * 64 + 2 * tid] = Zr; Lb[g2 * 64 + 2 * tid + 1] = Zi;
                float t_r = fmaf(Wseg.x, Zr, fmaf(-Wseg.y, Zi, lr_));
                float t_i = fmaf(Wseg.x, Zi, fmaf(Wseg.y, Zr, li_));
                Zr = t_r; Zi = t_i;
            }
        }
        __syncthreads();
        float pr = Lb[g * 64 + 2 * n], pi = Lb[g * 64 + 2 * n + 1];
        for (int c = g * SEGC; c < g * SEGC + SEGC; ++c) {
            int a0 = c * 64 + 2 * n, a1 = a0 + 1;
            S[a0] += pr; S[a1] += pi;
            float t_r = fmaf(W.x, pr, -W.y * pi);
            float t_i = fmaf(W.x, pi,  W.y * pr);
            pr = t_r; pi = t_i;
        }
    }
    __syncthreads();

    // ---- carry (fp32 VALU): S[c][lane] <- sum_m s0[c][m]*ef[m] ----
    // lane m holds s0[c][m]; readlane broadcast (own-wave chunks, wave-ordered LDS)
    for (int c = cbase; c < cbase + 32; ++c) {
        float sv = S[c * 64 + lane];
        float a0 = 0.f, a1 = 0.f, a2 = 0.f, a3 = 0.f;
        #pragma unroll
        for (int m = 0; m < 64; m += 4) {
            a0 = fmaf(__shfl(sv, m + 0), ef[m + 0], a0);
            a1 = fmaf(__shfl(sv, m + 1), ef[m + 1], a1);
            a2 = fmaf(__shfl(sv, m + 2), ef[m + 2], a2);
            a3 = fmaf(__shfl(sv, m + 3), ef[m + 3], a3);
        }
        S[c * 64 + lane] = (a0 + a1) + (a2 + a3);
    }
    __syncthreads();

    // ---- phase 3: y = U*K (MFMA) + carry ----
    float* yb = y + (size_t)bh * Lk;
    #pragma unroll
    for (int ct = 0; ct < 2; ++ct) {
        #pragma unroll
        for (int mt = 0; mt < 4; ++mt) {
            int tb = (((h << 2) + mt) << 1) * 64 + lane;
            short8 Kh0 = Khi[tb],      Kl0 = Klo[tb];
            short8 Kh1 = Khi[tb + 64], Kl1 = Klo[tb + 64];
            f32x4 a = {0.f, 0.f, 0.f, 0.f};
            a = mfma16(Uhi[ct][0], Kh0, a);
            a = mfma16(Ulo[ct][0], Kh0, a);
            a = mfma16(Uhi[ct][0], Kl0, a);
            a = mfma16(Uhi[ct][1], Kh1, a);
            a = mfma16(Ulo[ct][1], Kh1, a);
            a = mfma16(Uhi[ct][1], Kl1, a);
            #pragma unroll
            for (int r = 0; r < 4; ++r) {
                int row = cbase + ct * 16 + lq * 4 + r;
                yb[(size_t)row * 64 + mt * 16 + lr] = a[r] + S[row * 64 + mt * 16 + lr];
            }
        }
    }
}

extern "C" void kernel_launch(void* const* d_in, const int* in_sizes, int n_in,
                              void* d_out, int out_size, void* d_ws, size_t ws_size,
                              hipStream_t stream) {
    const float* u          = (const float*)d_in[0];
    const float* log_dt     = (const float*)d_in[1];
    const float* log_A_real = (const float*)d_in[2];
    const float* A_imag     = (const float*)d_in[3];
    const float* C          = (const float*)d_in[4];
    const float* D          = (const float*)d_in[5];
    float* y = (float*)d_out;

    char* ws = (char*)d_ws;
    double* MD     = (double*)(ws);
    float2* WS64   = (float2*)(ws + 262144);
    float2* WS1024 = (float2*)(ws + 327680);
    double* kvecd  = (double*)(ws + 393216);
    short*  Phi    = (short*)(ws + 524288);
    short*  Plo    = (short*)(ws + 2621440);
    short*  Khi    = (short*)(ws + 4718592);
    short*  Klo    = (short*)(ws + 6815744);
    float*  Ef     = (float*)(ws + 8912896);

    s4d_p0<<<(Hk * N2k) / 256, 256, 0, stream>>>(log_dt, log_A_real, A_imag, C,
                                                 MD, WS64, WS1024);
    s4d_pk<<<(Hk * 64) / 256, 256, 0, stream>>>(MD, D, kvecd);
    s4d_pp<<<(Hk * 64) / 256, 256, 0, stream>>>(MD, Phi, Plo);
    s4d_pkk<<<(Hk * 64) / 256, 256, 0, stream>>>(kvecd, Khi, Klo);
    s4d_pe<<<(Hk * N2k) / 256, 256, 0, stream>>>(MD, Ef);
    s4d_mm2<<<Bk * Hk, 256, 0, stream>>>(u, (const short8*)Phi, (const short8*)Plo,
                                         (const short8*)Khi, (const short8*)Klo,
                                         Ef, WS64, WS1024, y);
}

// Round 5
// 373.937 us; speedup vs baseline: 3.3845x; 1.8642x over previous
//
#include <hip/hip_runtime.h>

#define Bk 16
#define Hk 256
#define Lk 8192
#define N2k 32
#define Tk 64            // chunk length
#define Gk 128           // chunks per (b,h)
#define NSEG 8           // scan segments
#define SEGC 16          // chunks per segment

typedef __attribute__((ext_vector_type(8))) short short8;
typedef __attribute__((ext_vector_type(4))) float f32x4;

__device__ __forceinline__ f32x4 mfma16(short8 a, short8 b, f32x4 c) {
    return __builtin_amdgcn_mfma_f32_16x16x32_bf16(a, b, c, 0, 0, 0);
}

__device__ __forceinline__ void split1(float x, short& hi, short& lo) {
    __bf16 h = (__bf16)x;
    __bf16 l = (__bf16)(x - (float)h);
    hi = __builtin_bit_cast(short, h);
    lo = __builtin_bit_cast(short, l);
}

// readlane broadcast: lane index must be compile-time/uniform
#define RLANE(v, i) __int_as_float(__builtin_amdgcn_readlane(__float_as_int(v), (i)))

// short index inside the packed fragment tables for (h, col, k):
//   frag8 index = (((h*4 + col/16)*2 + k/32)*64 + ((k>>3)&3)*16 + (col&15)), elem = k&7
__device__ __forceinline__ int frag_sidx(int h, int col, int k) {
    int mt = col >> 4, kh = k >> 5;
    int lane = (((k >> 3) & 3) << 4) | (col & 15);
    return ((((((h << 2) + mt) << 1) + kh) << 6) + lane) * 8 + (k & 7);
}

// Workspace layout (bytes), ~12.9 MB total:
//   MD     double[H*N2*4]  @ 0        {dr, di, ctr, cti}
//   WS64   float2[H*N2]    @ 262144   w^64
//   WS1024 float2[H*N2]    @ 327680   w^1024
//   kvecd  double[H*64]    @ 393216   conv kernel k[d] (k[0] += D)
//   Phi    short[H*64*64]  @ 524288
//   Plo    short[H*64*64]  @ 2621440
//   Khi    short[H*64*64]  @ 4718592
//   Klo    short[H*64*64]  @ 6815744
//   Ef     float[H*64*64]  @ 8912896  Ef[(h*64+l)*64 + m], m=2n:Re(ct*w^(l+1)), 2n+1:-Im

__global__ void s4d_p0(const float* __restrict__ log_dt,
                       const float* __restrict__ log_A_real,
                       const float* __restrict__ A_imag,
                       const float* __restrict__ C,
                       double* __restrict__ MD,
                       float2* __restrict__ WS64,
                       float2* __restrict__ WS1024) {
    int t = blockIdx.x * blockDim.x + threadIdx.x;
    if (t >= Hk * N2k) return;
    int h = t >> 5;
    double dt  = exp((double)log_dt[h]);
    double are = -exp((double)log_A_real[t]);
    double aim = (double)A_imag[t];
    double dr = dt * are, di = dt * aim;
    double er = exp(dr);
    double wre = er * cos(di), wim = er * sin(di);
    double denom = are * are + aim * aim;
    double tr = wre - 1.0, ti = wim;
    double qr = (tr * are + ti * aim) / denom;   // (w-1)/A
    double qi = (ti * are - tr * aim) / denom;
    double c0 = (double)C[2 * t], c1 = (double)C[2 * t + 1];
    double ctr = 2.0 * (c0 * qr - c1 * qi);
    double cti = 2.0 * (c0 * qi + c1 * qr);
    MD[4 * t] = dr; MD[4 * t + 1] = di; MD[4 * t + 2] = ctr; MD[4 * t + 3] = cti;
    double e64 = exp(64.0 * dr), a64 = 64.0 * di;
    WS64[t] = make_float2((float)(e64 * cos(a64)), (float)(e64 * sin(a64)));
    double eS = exp(1024.0 * dr), aS = 1024.0 * di;
    WS1024[t] = make_float2((float)(eS * cos(aS)), (float)(eS * sin(aS)));
}

__global__ void s4d_pk(const double* __restrict__ MD, const float* __restrict__ Dv,
                       double* __restrict__ kvecd) {
    int t = blockIdx.x * blockDim.x + threadIdx.x; // (h, d)
    if (t >= Hk * 64) return;
    int h = t >> 6, d = t & 63;
    double acc = 0.0;
    for (int n = 0; n < N2k; ++n) {
        const double* md = MD + 4 * ((h << 5) + n);
        double e = exp((double)d * md[0]), a = (double)d * md[1];
        acc += md[2] * (e * cos(a)) - md[3] * (e * sin(a));
    }
    if (d == 0) acc += (double)Dv[h];
    kvecd[t] = acc;
}

// P table via recurrence (verified round 3): thread per (h, m)
__global__ void s4d_pp(const double* __restrict__ MD,
                       short* __restrict__ Phi, short* __restrict__ Plo) {
    int t = blockIdx.x * blockDim.x + threadIdx.x;
    if (t >= Hk * 64) return;
    int h = t >> 6, m = t & 63, n = m >> 1;
    const double* md = MD + 4 * ((h << 5) + n);
    double er = exp(md[0]);
    double wre = er * cos(md[1]), wim = er * sin(md[1]);
    double cr = 1.0, ci = 0.0;                    // w^0
    for (int p = 0; p < 64; ++p) {                // power p at k = 63-p
        float val = (float)((m & 1) ? ci : cr);
        short hi, lo; split1(val, hi, lo);
        int si = frag_sidx(h, m, 63 - p);
        Phi[si] = hi; Plo[si] = lo;
        double nr = cr * wre - ci * wim;
        double nc = cr * wim + ci * wre;
        cr = nr; ci = nc;
    }
}

// K table, parallel: thread per (h, col, k) — value-identical to round-3 pkk
__global__ void s4d_pkk(const double* __restrict__ kvecd,
                        short* __restrict__ Khi, short* __restrict__ Klo) {
    int t = blockIdx.x * blockDim.x + threadIdx.x;
    if (t >= Hk * 64 * 64) return;
    int k = t & 63, col = (t >> 6) & 63, h = t >> 12;
    float val = (k <= col) ? (float)kvecd[(h << 6) + col - k] : 0.f;
    short hi, lo; split1(val, hi, lo);
    int si = frag_sidx(h, col, k);
    Khi[si] = hi; Klo[si] = lo;
}

// Ef via recurrence (verified round 3): thread per (h, n); cur = ct*w^(l+1)
__global__ void s4d_pe(const double* __restrict__ MD, float* __restrict__ Ef) {
    int t = blockIdx.x * blockDim.x + threadIdx.x;
    if (t >= Hk * N2k) return;
    int h = t >> 5, n = t & 31;
    const double* md = MD + 4 * t;
    double er = exp(md[0]);
    double wre = er * cos(md[1]), wim = er * sin(md[1]);
    double cr = md[2] * wre - md[3] * wim;        // ct * w^1
    double ci = md[2] * wim + md[3] * wre;
    for (int l = 0; l < 64; ++l) {
        float* row = Ef + (((size_t)(h << 6) + l) << 6);
        row[2 * n]     = (float)cr;
        row[2 * n + 1] = (float)(-ci);
        double nr = cr * wre - ci * wim;
        double nc = cr * wim + ci * wre;
        cr = nr; ci = nc;
    }
}

// Fused main kernel: one wg (4 waves) per (b,h); wave wv owns chunks [32wv, 32wv+32).
// Phase 1 (MFMA): V^T = U^T * P^T -> LDS S (linear [c][m])
// Phase 2: segmented exclusive chunk scan (fp32)
// Carry (fp32 VALU): S[c][l] <- sum_m s0[c][m] * Ef[h][l][m]  via v_readlane (no LDS pipe)
// Phase 3 (MFMA): y = U^T * K^T + carry
__global__ __launch_bounds__(256) void s4d_mm2(
    const float* __restrict__ u,
    const short8* __restrict__ Phi, const short8* __restrict__ Plo,
    const short8* __restrict__ Khi, const short8* __restrict__ Klo,
    const float* __restrict__ Ef,
    const float2* __restrict__ WS64, const float2* __restrict__ WS1024,
    float* __restrict__ y) {
    __shared__ __align__(16) float S[Gk * Tk];   // 32 KB
    __shared__ float Lb[NSEG * 64];              // 2 KB

    int b = blockIdx.x & (Bk - 1);
    int h = blockIdx.x >> 4;
    int bh = b * Hk + h;
    int tid = threadIdx.x;
    int lane = tid & 63, wv = tid >> 6;
    int lr = lane & 15, lq = lane >> 4;
    int cbase = wv * 32;
    const float* ub = u + (size_t)bh * Lk;

    // ---- U fragments: row c = cbase+ct*16+lr, k j = kh*32+lq*8+e
    short8 Uhi[2][2], Ulo[2][2];
    #pragma unroll
    for (int ct = 0; ct < 2; ++ct)
        #pragma unroll
        for (int kh = 0; kh < 2; ++kh) {
            const float* src = ub + (size_t)(cbase + ct * 16 + lr) * 64 + kh * 32 + lq * 8;
            float4 a4 = *(const float4*)src;
            float4 c4 = *(const float4*)(src + 4);
            float v[8] = {a4.x, a4.y, a4.z, a4.w, c4.x, c4.y, c4.z, c4.w};
            #pragma unroll
            for (int e = 0; e < 8; ++e) {
                short hi, lo; split1(v[e], hi, lo);
                Uhi[ct][kh][e] = hi; Ulo[ct][kh][e] = lo;
            }
        }

    // ---- phase 1: V -> S (linear) ----
    #pragma unroll
    for (int mt = 0; mt < 4; ++mt) {
        int tb = (((h << 2) + mt) << 1) * 64 + lane;
        short8 Bh0 = Phi[tb], Bl0 = Plo[tb];
        short8 Bh1 = Phi[tb + 64], Bl1 = Plo[tb + 64];
        #pragma unroll
        for (int ct = 0; ct < 2; ++ct) {
            f32x4 a = {0.f, 0.f, 0.f, 0.f};
            a = mfma16(Uhi[ct][0], Bh0, a);
            a = mfma16(Ulo[ct][0], Bh0, a);
            a = mfma16(Uhi[ct][0], Bl0, a);
            a = mfma16(Uhi[ct][1], Bh1, a);
            a = mfma16(Ulo[ct][1], Bh1, a);
            a = mfma16(Uhi[ct][1], Bl1, a);
            #pragma unroll
            for (int r = 0; r < 4; ++r)
                S[(cbase + ct * 16 + lq * 4 + r) * 64 + mt * 16 + lr] = a[r];
        }
    }

    // ---- E-row load (overlaps scan latency): lane l = lane ----
    float ef[64];
    {
        const float4* er4 = (const float4*)(Ef + (((size_t)(h << 6) + lane) << 6));
        #pragma unroll
        for (int i = 0; i < 16; ++i) {
            float4 e4 = er4[i];
            ef[4 * i] = e4.x; ef[4 * i + 1] = e4.y; ef[4 * i + 2] = e4.z; ef[4 * i + 3] = e4.w;
        }
    }
    __syncthreads();

    // ---- phase 2: segmented exclusive scan, thread = (mode n, segment g) ----
    {
        int n = tid & 31, g = tid >> 5;
        float2 W = WS64[(h << 5) + n];
        float zr = 0.f, zi = 0.f;
        for (int c = g * SEGC; c < g * SEGC + SEGC; ++c) {
            int a0 = c * 64 + 2 * n, a1 = a0 + 1;
            float vr = S[a0], vi = S[a1];
            S[a0] = zr; S[a1] = zi;
            float t_r = fmaf(W.x, zr, fmaf(-W.y, zi, vr));
            float t_i = fmaf(W.x, zi, fmaf(W.y, zr, vi));
            zr = t_r; zi = t_i;
        }
        Lb[g * 64 + 2 * n] = zr; Lb[g * 64 + 2 * n + 1] = zi;
        __syncthreads();
        if (tid < 32) {
            float2 Wseg = WS1024[(h << 5) + tid];
            float Zr = 0.f, Zi = 0.f;
            for (int g2 = 0; g2 < NSEG; ++g2) {
                float lr_ = Lb[g2 * 64 + 2 * tid], li_ = Lb[g2 * 64 + 2 * tid + 1];
                Lb[g2 * 64 + 2 * tid] = Zr; Lb[g2 * 64 + 2 * tid + 1] = Zi;
                float t_r = fmaf(Wseg.x, Zr, fmaf(-Wseg.y, Zi, lr_));
                float t_i = fmaf(Wseg.x, Zi, fmaf(Wseg.y, Zr, li_));
                Zr = t_r; Zi = t_i;
            }
        }
        __syncthreads();
        float pr = Lb[g * 64 + 2 * n], pi = Lb[g * 64 + 2 * n + 1];
        for (int c = g * SEGC; c < g * SEGC + SEGC; ++c) {
            int a0 = c * 64 + 2 * n, a1 = a0 + 1;
            S[a0] += pr; S[a1] += pi;
            float t_r = fmaf(W.x, pr, -W.y * pi);
            float t_i = fmaf(W.x, pi,  W.y * pr);
            pr = t_r; pi = t_i;
        }
    }
    __syncthreads();

    // ---- carry (fp32 VALU): S[c][lane] <- sum_m s0[c][m]*ef[m] ----
    // lane m holds s0[c][m]; v_readlane broadcast (SGPR path, no ds_bpermute storm).
    // 2-deep prefetch hides the ~120cy ds_read latency under the 128-op body.
    {
        float svn = S[cbase * 64 + lane];
        for (int c = cbase; c < cbase + 32; ++c) {
            float sv = svn;
            if (c + 1 < cbase + 32) svn = S[(c + 1) * 64 + lane];
            float a0 = 0.f, a1 = 0.f, a2 = 0.f, a3 = 0.f;
            #pragma unroll
            for (int m = 0; m < 64; m += 4) {
                a0 = fmaf(RLANE(sv, m + 0), ef[m + 0], a0);
                a1 = fmaf(RLANE(sv, m + 1), ef[m + 1], a1);
                a2 = fmaf(RLANE(sv, m + 2), ef[m + 2], a2);
                a3 = fmaf(RLANE(sv, m + 3), ef[m + 3], a3);
            }
            S[c * 64 + lane] = (a0 + a1) + (a2 + a3);
        }
    }
    __syncthreads();

    // ---- phase 3: y = U*K (MFMA) + carry ----
    float* yb = y + (size_t)bh * Lk;
    #pragma unroll
    for (int ct = 0; ct < 2; ++ct) {
        #pragma unroll
        for (int mt = 0; mt < 4; ++mt) {
            int tb = (((h << 2) + mt) << 1) * 64 + lane;
            short8 Kh0 = Khi[tb],      Kl0 = Klo[tb];
            short8 Kh1 = Khi[tb + 64], Kl1 = Klo[tb + 64];
            f32x4 a = {0.f, 0.f, 0.f, 0.f};
            a = mfma16(Uhi[ct][0], Kh0, a);
            a = mfma16(Ulo[ct][0], Kh0, a);
            a = mfma16(Uhi[ct][0], Kl0, a);
            a = mfma16(Uhi[ct][1], Kh1, a);
            a = mfma16(Ulo[ct][1], Kh1, a);
            a = mfma16(Uhi[ct][1], Kl1, a);
            #pragma unroll
            for (int r = 0; r < 4; ++r) {
                int row = cbase + ct * 16 + lq * 4 + r;
                yb[(size_t)row * 64 + mt * 16 + lr] = a[r] + S[row * 64 + mt * 16 + lr];
            }
        }
    }
}

extern "C" void kernel_launch(void* const* d_in, const int* in_sizes, int n_in,
                              void* d_out, int out_size, void* d_ws, size_t ws_size,
                              hipStream_t stream) {
    const float* u          = (const float*)d_in[0];
    const float* log_dt     = (const float*)d_in[1];
    const float* log_A_real = (const float*)d_in[2];
    const float* A_imag     = (const float*)d_in[3];
    const float* C          = (const float*)d_in[4];
    const float* D          = (const float*)d_in[5];
    float* y = (float*)d_out;

    char* ws = (char*)d_ws;
    double* MD     = (double*)(ws);
    float2* WS64   = (float2*)(ws + 262144);
    float2* WS1024 = (float2*)(ws + 327680);
    double* kvecd  = (double*)(ws + 393216);
    short*  Phi    = (short*)(ws + 524288);
    short*  Plo    = (short*)(ws + 2621440);
    short*  Khi    = (short*)(ws + 4718592);
    short*  Klo    = (short*)(ws + 6815744);
    float*  Ef     = (float*)(ws + 8912896);

    s4d_p0<<<(Hk * N2k) / 256, 256, 0, stream>>>(log_dt, log_A_real, A_imag, C,
                                                 MD, WS64, WS1024);
    s4d_pk<<<(Hk * 64) / 256, 256, 0, stream>>>(MD, D, kvecd);
    s4d_pp<<<(Hk * 64) / 256, 256, 0, stream>>>(MD, Phi, Plo);
    s4d_pkk<<<(Hk * 64 * 64) / 256, 256, 0, stream>>>(kvecd, Khi, Klo);
    s4d_pe<<<(Hk * N2k) / 256, 256, 0, stream>>>(MD, Ef);
    s4d_mm2<<<Bk * Hk, 256, 0, stream>>>(u, (const short8*)Phi, (const short8*)Plo,
                                         (const short8*)Khi, (const short8*)Klo,
                                         Ef, WS64, WS1024, y);
}

// Round 6
// 371.591 us; speedup vs baseline: 3.4059x; 1.0063x over previous
//
#include <hip/hip_runtime.h>

#define Bk 16
#define Hk 256
#define Lk 8192
#define N2k 32
#define Tk 64            // chunk length
#define Gk 128           // chunks per (b,h)
#define NSEG 8           // scan segments
#define SEGC 16          // chunks per segment

typedef __attribute__((ext_vector_type(8))) short short8;
typedef __attribute__((ext_vector_type(4))) float f32x4;

__device__ __forceinline__ f32x4 mfma16(short8 a, short8 b, f32x4 c) {
    return __builtin_amdgcn_mfma_f32_16x16x32_bf16(a, b, c, 0, 0, 0);
}

__device__ __forceinline__ void split1(float x, short& hi, short& lo) {
    __bf16 h = (__bf16)x;
    __bf16 l = (__bf16)(x - (float)h);
    hi = __builtin_bit_cast(short, h);
    lo = __builtin_bit_cast(short, l);
}

// readlane broadcast: lane index must be compile-time/uniform
#define RLANE(v, i) __int_as_float(__builtin_amdgcn_readlane(__float_as_int(v), (i)))

// Workspace layout (bytes), ~13.3 MB total:
//   MD     double[H*N2*4]  @ 0        {dr, di, ctr, cti}
//   WS64   float2[H*N2]    @ 262144   w^64
//   WS1024 float2[H*N2]    @ 327680   w^1024
//   kpart  float[H*64*4]   @ 393216   partial kvec sums (8 modes each)
//   kvec   float[H*64]     @ 655360   conv kernel k[d] (k[0] += D)
//   Phi    short[H*64*64]  @ 720896
//   Plo    short[H*64*64]  @ 2818048
//   Khi    short[H*64*64]  @ 4915200
//   Klo    short[H*64*64]  @ 7012352
//   Ef     float[H*64*64]  @ 9109504  Ef[(h*64+l)*64+m]: m=2n Re(ct*w^(l+1)), 2n+1 -Im

__global__ void s4d_p0(const float* __restrict__ log_dt,
                       const float* __restrict__ log_A_real,
                       const float* __restrict__ A_imag,
                       const float* __restrict__ C,
                       double* __restrict__ MD,
                       float2* __restrict__ WS64,
                       float2* __restrict__ WS1024) {
    int t = blockIdx.x * blockDim.x + threadIdx.x;
    if (t >= Hk * N2k) return;
    int h = t >> 5;
    double dt  = exp((double)log_dt[h]);
    double are = -exp((double)log_A_real[t]);
    double aim = (double)A_imag[t];
    double dr = dt * are, di = dt * aim;
    double er = exp(dr);
    double wre = er * cos(di), wim = er * sin(di);
    double denom = are * are + aim * aim;
    double tr = wre - 1.0, ti = wim;
    double qr = (tr * are + ti * aim) / denom;   // (w-1)/A
    double qi = (ti * are - tr * aim) / denom;
    double c0 = (double)C[2 * t], c1 = (double)C[2 * t + 1];
    double ctr = 2.0 * (c0 * qr - c1 * qi);
    double cti = 2.0 * (c0 * qi + c1 * qr);
    MD[4 * t] = dr; MD[4 * t + 1] = di; MD[4 * t + 2] = ctr; MD[4 * t + 3] = cti;
    double e64 = exp(64.0 * dr), a64 = 64.0 * di;
    WS64[t] = make_float2((float)(e64 * cos(a64)), (float)(e64 * sin(a64)));
    double eS = exp(1024.0 * dr), aS = 1024.0 * di;
    WS1024[t] = make_float2((float)(eS * cos(aS)), (float)(eS * sin(aS)));
}

// kvec partials: thread per (h, d, g); sums modes [8g, 8g+8)
__global__ void s4d_kvp(const double* __restrict__ MD, float* __restrict__ kpart) {
    int t = blockIdx.x * blockDim.x + threadIdx.x;
    if (t >= Hk * 64 * 4) return;
    int g = t & 3, d = (t >> 2) & 63, h = t >> 8;
    double acc = 0.0;
    #pragma unroll
    for (int j = 0; j < 8; ++j) {
        const double* md = MD + 4 * ((h << 5) + 8 * g + j);
        double e = exp((double)d * md[0]), a = (double)d * md[1];
        acc += md[2] * (e * cos(a)) - md[3] * (e * sin(a));
    }
    kpart[t] = (float)acc;
}

// kvec reduce: thread per (h, d)
__global__ void s4d_kv2(const float* __restrict__ kpart, const float* __restrict__ Dv,
                        float* __restrict__ kvec) {
    int t = blockIdx.x * blockDim.x + threadIdx.x;
    if (t >= Hk * 64) return;
    int d = t & 63, h = t >> 6;
    float v = (kpart[4 * t] + kpart[4 * t + 1]) + (kpart[4 * t + 2] + kpart[4 * t + 3]);
    if (d == 0) v += Dv[h];
    kvec[t] = v;
}

// P + K pack: one thread per short8 fragment slot t = ((h*4+mt)*2+kh)*64+lane.
// col = mt*16+(lane&15); k = kbase+e, kbase = kh*32+((lane>>4)<<3).
// Slot layout verified identical to round-5 frag_sidx (t == frag_sidx/8).
//   P[col][k] = Re/Im(w_{col>>1}^(63-k)): trig start at power 56-kbase, ascend 8.
//   K[col][k] = kvec[col-k] (0 if k>col).
__global__ void s4d_packPK(const double* __restrict__ MD,
                           const float* __restrict__ kvec,
                           short8* __restrict__ Phi, short8* __restrict__ Plo,
                           short8* __restrict__ Khi, short8* __restrict__ Klo) {
    int t = blockIdx.x * blockDim.x + threadIdx.x;
    if (t >= Hk * 512) return;
    int lane = t & 63, kh = (t >> 6) & 1, mt = (t >> 7) & 3, h = t >> 9;
    int col = mt * 16 + (lane & 15);
    int kbase = kh * 32 + ((lane >> 4) << 3);
    // P
    {
        const double* md = MD + 4 * ((h << 5) + (col >> 1));
        double dr = md[0], di = md[1];
        double er = exp(dr);
        double wre = er * cos(di), wim = er * sin(di);
        double ps = (double)(56 - kbase);             // power at k = kbase+7
        double ezr = exp(ps * dr), ang = ps * di;
        double zr = ezr * cos(ang), zi = ezr * sin(ang);
        float pv[8];
        #pragma unroll
        for (int j = 0; j < 8; ++j) {                 // power ps+j  <->  k = kbase+7-j
            pv[7 - j] = (float)((col & 1) ? zi : zr);
            double nr = zr * wre - zi * wim;
            double ni = zr * wim + zi * wre;
            zr = nr; zi = ni;
        }
        short8 hi, lo;
        #pragma unroll
        for (int e = 0; e < 8; ++e) { short a1, b1; split1(pv[e], a1, b1); hi[e] = a1; lo[e] = b1; }
        Phi[t] = hi; Plo[t] = lo;
    }
    // K
    {
        short8 hi, lo;
        #pragma unroll
        for (int e = 0; e < 8; ++e) {
            int k = kbase + e;
            float v = (k <= col) ? kvec[(h << 6) + col - k] : 0.f;
            short a1, b1; split1(v, a1, b1); hi[e] = a1; lo[e] = b1;
        }
        Khi[t] = hi; Klo[t] = lo;
    }
}

// Ef direct: thread per (h, l, n); Ef2[(h*64+l)*32+n] = {Re(ct*w^(l+1)), -Im(...)}
__global__ void s4d_pe2(const double* __restrict__ MD, float2* __restrict__ Ef2) {
    int t = blockIdx.x * blockDim.x + threadIdx.x;
    if (t >= Hk * 64 * 32) return;
    int n = t & 31, l = (t >> 5) & 63, h = t >> 11;
    const double* md = MD + 4 * ((h << 5) + n);
    double p = (double)(l + 1);
    double e = exp(p * md[0]), a = p * md[1];
    double re = e * cos(a), im = e * sin(a);
    double cr = md[2] * re - md[3] * im;
    double ci = md[2] * im + md[3] * re;
    Ef2[t] = make_float2((float)cr, (float)(-ci));
}

// Fused main kernel — byte-identical to the passing round-5 version.
// Phase 1 (MFMA): V^T = U^T * P^T -> LDS S (linear [c][m])
// Phase 2: segmented exclusive chunk scan (fp32)
// Carry (fp32 VALU): S[c][l] <- sum_m s0[c][m] * Ef[h][l][m]  via v_readlane
// Phase 3 (MFMA): y = U^T * K^T + carry
__global__ __launch_bounds__(256) void s4d_mm2(
    const float* __restrict__ u,
    const short8* __restrict__ Phi, const short8* __restrict__ Plo,
    const short8* __restrict__ Khi, const short8* __restrict__ Klo,
    const float* __restrict__ Ef,
    const float2* __restrict__ WS64, const float2* __restrict__ WS1024,
    float* __restrict__ y) {
    __shared__ __align__(16) float S[Gk * Tk];   // 32 KB
    __shared__ float Lb[NSEG * 64];              // 2 KB

    int b = blockIdx.x & (Bk - 1);
    int h = blockIdx.x >> 4;
    int bh = b * Hk + h;
    int tid = threadIdx.x;
    int lane = tid & 63, wv = tid >> 6;
    int lr = lane & 15, lq = lane >> 4;
    int cbase = wv * 32;
    const float* ub = u + (size_t)bh * Lk;

    // ---- U fragments: row c = cbase+ct*16+lr, k j = kh*32+lq*8+e
    short8 Uhi[2][2], Ulo[2][2];
    #pragma unroll
    for (int ct = 0; ct < 2; ++ct)
        #pragma unroll
        for (int kh = 0; kh < 2; ++kh) {
            const float* src = ub + (size_t)(cbase + ct * 16 + lr) * 64 + kh * 32 + lq * 8;
            float4 a4 = *(const float4*)src;
            float4 c4 = *(const float4*)(src + 4);
            float v[8] = {a4.x, a4.y, a4.z, a4.w, c4.x, c4.y, c4.z, c4.w};
            #pragma unroll
            for (int e = 0; e < 8; ++e) {
                short hi, lo; split1(v[e], hi, lo);
                Uhi[ct][kh][e] = hi; Ulo[ct][kh][e] = lo;
            }
        }

    // ---- phase 1: V -> S (linear) ----
    #pragma unroll
    for (int mt = 0; mt < 4; ++mt) {
        int tb = (((h << 2) + mt) << 1) * 64 + lane;
        short8 Bh0 = Phi[tb], Bl0 = Plo[tb];
        short8 Bh1 = Phi[tb + 64], Bl1 = Plo[tb + 64];
        #pragma unroll
        for (int ct = 0; ct < 2; ++ct) {
            f32x4 a = {0.f, 0.f, 0.f, 0.f};
            a = mfma16(Uhi[ct][0], Bh0, a);
            a = mfma16(Ulo[ct][0], Bh0, a);
            a = mfma16(Uhi[ct][0], Bl0, a);
            a = mfma16(Uhi[ct][1], Bh1, a);
            a = mfma16(Ulo[ct][1], Bh1, a);
            a = mfma16(Uhi[ct][1], Bl1, a);
            #pragma unroll
            for (int r = 0; r < 4; ++r)
                S[(cbase + ct * 16 + lq * 4 + r) * 64 + mt * 16 + lr] = a[r];
        }
    }

    // ---- E-row load (overlaps scan latency): lane l = lane ----
    float ef[64];
    {
        const float4* er4 = (const float4*)(Ef + (((size_t)(h << 6) + lane) << 6));
        #pragma unroll
        for (int i = 0; i < 16; ++i) {
            float4 e4 = er4[i];
            ef[4 * i] = e4.x; ef[4 * i + 1] = e4.y; ef[4 * i + 2] = e4.z; ef[4 * i + 3] = e4.w;
        }
    }
    __syncthreads();

    // ---- phase 2: segmented exclusive scan, thread = (mode n, segment g) ----
    {
        int n = tid & 31, g = tid >> 5;
        float2 W = WS64[(h << 5) + n];
        float zr = 0.f, zi = 0.f;
        for (int c = g * SEGC; c < g * SEGC + SEGC; ++c) {
            int a0 = c * 64 + 2 * n, a1 = a0 + 1;
            float vr = S[a0], vi = S[a1];
            S[a0] = zr; S[a1] = zi;
            float t_r = fmaf(W.x, zr, fmaf(-W.y, zi, vr));
            float t_i = fmaf(W.x, zi, fmaf(W.y, zr, vi));
            zr = t_r; zi = t_i;
        }
        Lb[g * 64 + 2 * n] = zr; Lb[g * 64 + 2 * n + 1] = zi;
        __syncthreads();
        if (tid < 32) {
            float2 Wseg = WS1024[(h << 5) + tid];
            float Zr = 0.f, Zi = 0.f;
            for (int g2 = 0; g2 < NSEG; ++g2) {
                float lr_ = Lb[g2 * 64 + 2 * tid], li_ = Lb[g2 * 64 + 2 * tid + 1];
                Lb[g2 * 64 + 2 * tid] = Zr; Lb[g2 * 64 + 2 * tid + 1] = Zi;
                float t_r = fmaf(Wseg.x, Zr, fmaf(-Wseg.y, Zi, lr_));
                float t_i = fmaf(Wseg.x, Zi, fmaf(Wseg.y, Zr, li_));
                Zr = t_r; Zi = t_i;
            }
        }
        __syncthreads();
        float pr = Lb[g * 64 + 2 * n], pi = Lb[g * 64 + 2 * n + 1];
        for (int c = g * SEGC; c < g * SEGC + SEGC; ++c) {
            int a0 = c * 64 + 2 * n, a1 = a0 + 1;
            S[a0] += pr; S[a1] += pi;
            float t_r = fmaf(W.x, pr, -W.y * pi);
            float t_i = fmaf(W.x, pi,  W.y * pr);
            pr = t_r; pi = t_i;
        }
    }
    __syncthreads();

    // ---- carry (fp32 VALU): S[c][lane] <- sum_m s0[c][m]*ef[m] ----
    {
        float svn = S[cbase * 64 + lane];
        for (int c = cbase; c < cbase + 32; ++c) {
            float sv = svn;
            if (c + 1 < cbase + 32) svn = S[(c + 1) * 64 + lane];
            float a0 = 0.f, a1 = 0.f, a2 = 0.f, a3 = 0.f;
            #pragma unroll
            for (int m = 0; m < 64; m += 4) {
                a0 = fmaf(RLANE(sv, m + 0), ef[m + 0], a0);
                a1 = fmaf(RLANE(sv, m + 1), ef[m + 1], a1);
                a2 = fmaf(RLANE(sv, m + 2), ef[m + 2], a2);
                a3 = fmaf(RLANE(sv, m + 3), ef[m + 3], a3);
            }
            S[c * 64 + lane] = (a0 + a1) + (a2 + a3);
        }
    }
    __syncthreads();

    // ---- phase 3: y = U*K (MFMA) + carry ----
    float* yb = y + (size_t)bh * Lk;
    #pragma unroll
    for (int ct = 0; ct < 2; ++ct) {
        #pragma unroll
        for (int mt = 0; mt < 4; ++mt) {
            int tb = (((h << 2) + mt) << 1) * 64 + lane;
            short8 Kh0 = Khi[tb],      Kl0 = Klo[tb];
            short8 Kh1 = Khi[tb + 64], Kl1 = Klo[tb + 64];
            f32x4 a = {0.f, 0.f, 0.f, 0.f};
            a = mfma16(Uhi[ct][0], Kh0, a);
            a = mfma16(Ulo[ct][0], Kh0, a);
            a = mfma16(Uhi[ct][0], Kl0, a);
            a = mfma16(Uhi[ct][1], Kh1, a);
            a = mfma16(Ulo[ct][1], Kh1, a);
            a = mfma16(Uhi[ct][1], Kl1, a);
            #pragma unroll
            for (int r = 0; r < 4; ++r) {
                int row = cbase + ct * 16 + lq * 4 + r;
                yb[(size_t)row * 64 + mt * 16 + lr] = a[r] + S[row * 64 + mt * 16 + lr];
            }
        }
    }
}

extern "C" void kernel_launch(void* const* d_in, const int* in_sizes, int n_in,
                              void* d_out, int out_size, void* d_ws, size_t ws_size,
                              hipStream_t stream) {
    const float* u          = (const float*)d_in[0];
    const float* log_dt     = (const float*)d_in[1];
    const float* log_A_real = (const float*)d_in[2];
    const float* A_imag     = (const float*)d_in[3];
    const float* C          = (const float*)d_in[4];
    const float* D          = (const float*)d_in[5];
    float* y = (float*)d_out;

    char* ws = (char*)d_ws;
    double* MD     = (double*)(ws);
    float2* WS64   = (float2*)(ws + 262144);
    float2* WS1024 = (float2*)(ws + 327680);
    float*  kpart  = (float*) (ws + 393216);
    float*  kvec   = (float*) (ws + 655360);
    short*  Phi    = (short*) (ws + 720896);
    short*  Plo    = (short*) (ws + 2818048);
    short*  Khi    = (short*) (ws + 4915200);
    short*  Klo    = (short*) (ws + 7012352);
    float*  Ef     = (float*) (ws + 9109504);

    s4d_p0<<<(Hk * N2k) / 256, 256, 0, stream>>>(log_dt, log_A_real, A_imag, C,
                                                 MD, WS64, WS1024);
    s4d_kvp<<<(Hk * 64 * 4) / 256, 256, 0, stream>>>(MD, kpart);
    s4d_kv2<<<(Hk * 64) / 256, 256, 0, stream>>>(kpart, D, kvec);
    s4d_packPK<<<(Hk * 512) / 256, 256, 0, stream>>>(MD, kvec,
                                                     (short8*)Phi, (short8*)Plo,
                                                     (short8*)Khi, (short8*)Klo);
    s4d_pe2<<<(Hk * 64 * 32) / 256, 256, 0, stream>>>(MD, (float2*)Ef);
    s4d_mm2<<<Bk * Hk, 256, 0, stream>>>(u, (const short8*)Phi, (const short8*)Plo,
                                         (const short8*)Khi, (const short8*)Klo,
                                         Ef, WS64, WS1024, y);
}

// Round 8
// 321.073 us; speedup vs baseline: 3.9418x; 1.1573x over previous
//
#include <hip/hip_runtime.h>

#define Bk 16
#define Hk 256
#define Lk 8192
#define N2k 32
#define Tk 64            // chunk length
#define Gk 128           // chunks per (b,h)
#define NSEG 8           // scan segments
#define SEGC 16          // chunks per segment

typedef __attribute__((ext_vector_type(8))) short short8;
typedef __attribute__((ext_vector_type(4))) float f32x4;

__device__ __forceinline__ f32x4 mfma16(short8 a, short8 b, f32x4 c) {
    return __builtin_amdgcn_mfma_f32_16x16x32_bf16(a, b, c, 0, 0, 0);
}

__device__ __forceinline__ void split1(float x, short& hi, short& lo) {
    __bf16 h = (__bf16)x;
    __bf16 l = (__bf16)(x - (float)h);
    hi = __builtin_bit_cast(short, h);
    lo = __builtin_bit_cast(short, l);
}

// Workspace layout (bytes), ~17.5 MB total:
//   MD     double[H*N2*4]  @ 0        {dr, di, ctr, cti}
//   WS64   float2[H*N2]    @ 262144   w^64
//   WS1024 float2[H*N2]    @ 327680   w^1024
//   kpart  float[H*64*4]   @ 393216   partial kvec sums (8 modes each)
//   kvec   float[H*64]     @ 655360   conv kernel k[d] (k[0] += D)
//   Phi    short[H*64*64]  @ 720896
//   Plo    short[H*64*64]  @ 2818048
//   Khi    short[H*64*64]  @ 4915200
//   Klo    short[H*64*64]  @ 7012352
//   Ef2    float2[H*64*32] @ 9109504  Ef2[(h*64+l)*32+n] = {Re(ct*w^(l+1)), -Im(...)}
//   Ehi    short[H*64*64]  @ 13303808 (E in packPK slot layout, bf16 hi)
//   Elo    short[H*64*64]  @ 15400960

__global__ void s4d_p0(const float* __restrict__ log_dt,
                       const float* __restrict__ log_A_real,
                       const float* __restrict__ A_imag,
                       const float* __restrict__ C,
                       double* __restrict__ MD,
                       float2* __restrict__ WS64,
                       float2* __restrict__ WS1024) {
    int t = blockIdx.x * blockDim.x + threadIdx.x;
    if (t >= Hk * N2k) return;
    int h = t >> 5;
    double dt  = exp((double)log_dt[h]);
    double are = -exp((double)log_A_real[t]);
    double aim = (double)A_imag[t];
    double dr = dt * are, di = dt * aim;
    double er = exp(dr);
    double wre = er * cos(di), wim = er * sin(di);
    double denom = are * are + aim * aim;
    double tr = wre - 1.0, ti = wim;
    double qr = (tr * are + ti * aim) / denom;   // (w-1)/A
    double qi = (ti * are - tr * aim) / denom;
    double c0 = (double)C[2 * t], c1 = (double)C[2 * t + 1];
    double ctr = 2.0 * (c0 * qr - c1 * qi);
    double cti = 2.0 * (c0 * qi + c1 * qr);
    MD[4 * t] = dr; MD[4 * t + 1] = di; MD[4 * t + 2] = ctr; MD[4 * t + 3] = cti;
    double e64 = exp(64.0 * dr), a64 = 64.0 * di;
    WS64[t] = make_float2((float)(e64 * cos(a64)), (float)(e64 * sin(a64)));
    double eS = exp(1024.0 * dr), aS = 1024.0 * di;
    WS1024[t] = make_float2((float)(eS * cos(aS)), (float)(eS * sin(aS)));
}

// kvec partials: thread per (h, d, g); sums modes [8g, 8g+8)
__global__ void s4d_kvp(const double* __restrict__ MD, float* __restrict__ kpart) {
    int t = blockIdx.x * blockDim.x + threadIdx.x;
    if (t >= Hk * 64 * 4) return;
    int g = t & 3, d = (t >> 2) & 63, h = t >> 8;
    double acc = 0.0;
    #pragma unroll
    for (int j = 0; j < 8; ++j) {
        const double* md = MD + 4 * ((h << 5) + 8 * g + j);
        double e = exp((double)d * md[0]), a = (double)d * md[1];
        acc += md[2] * (e * cos(a)) - md[3] * (e * sin(a));
    }
    kpart[t] = (float)acc;
}

// kvec reduce: thread per (h, d)
__global__ void s4d_kv2(const float* __restrict__ kpart, const float* __restrict__ Dv,
                        float* __restrict__ kvec) {
    int t = blockIdx.x * blockDim.x + threadIdx.x;
    if (t >= Hk * 64) return;
    int d = t & 63, h = t >> 6;
    float v = (kpart[4 * t] + kpart[4 * t + 1]) + (kpart[4 * t + 2] + kpart[4 * t + 3]);
    if (d == 0) v += Dv[h];
    kvec[t] = v;
}

// P + K pack (verified round 6): one thread per short8 fragment slot
// t = ((h*4+mt)*2+kh)*64+lane; col = mt*16+(lane&15); k = kbase+e.
__global__ void s4d_packPK(const double* __restrict__ MD,
                           const float* __restrict__ kvec,
                           short8* __restrict__ Phi, short8* __restrict__ Plo,
                           short8* __restrict__ Khi, short8* __restrict__ Klo) {
    int t = blockIdx.x * blockDim.x + threadIdx.x;
    if (t >= Hk * 512) return;
    int lane = t & 63, kh = (t >> 6) & 1, mt = (t >> 7) & 3, h = t >> 9;
    int col = mt * 16 + (lane & 15);
    int kbase = kh * 32 + ((lane >> 4) << 3);
    // P
    {
        const double* md = MD + 4 * ((h << 5) + (col >> 1));
        double dr = md[0], di = md[1];
        double er = exp(dr);
        double wre = er * cos(di), wim = er * sin(di);
        double ps = (double)(56 - kbase);             // power at k = kbase+7
        double ezr = exp(ps * dr), ang = ps * di;
        double zr = ezr * cos(ang), zi = ezr * sin(ang);
        float pv[8];
        #pragma unroll
        for (int j = 0; j < 8; ++j) {                 // power ps+j  <->  k = kbase+7-j
            pv[7 - j] = (float)((col & 1) ? zi : zr);
            double nr = zr * wre - zi * wim;
            double ni = zr * wim + zi * wre;
            zr = nr; zi = ni;
        }
        short8 hi, lo;
        #pragma unroll
        for (int e = 0; e < 8; ++e) { short a1, b1; split1(pv[e], a1, b1); hi[e] = a1; lo[e] = b1; }
        Phi[t] = hi; Plo[t] = lo;
    }
    // K
    {
        short8 hi, lo;
        #pragma unroll
        for (int e = 0; e < 8; ++e) {
            int k = kbase + e;
            float v = (k <= col) ? kvec[(h << 6) + col - k] : 0.f;
            short a1, b1; split1(v, a1, b1); hi[e] = a1; lo[e] = b1;
        }
        Khi[t] = hi; Klo[t] = lo;
    }
}

// Ef2 direct (verified round 6): thread per (h, l, n)
__global__ void s4d_pe2(const double* __restrict__ MD, float2* __restrict__ Ef2) {
    int t = blockIdx.x * blockDim.x + threadIdx.x;
    if (t >= Hk * 64 * 32) return;
    int n = t & 31, l = (t >> 5) & 63, h = t >> 11;
    const double* md = MD + 4 * ((h << 5) + n);
    double p = (double)(l + 1);
    double e = exp(p * md[0]), a = p * md[1];
    double re = e * cos(a), im = e * sin(a);
    double cr = md[2] * re - md[3] * im;
    double ci = md[2] * im + md[3] * re;
    Ef2[t] = make_float2((float)cr, (float)(-ci));
}

// E fragment pack — pure reformat of the VERIFIED Ef2 table into the
// VERIFIED packPK slot layout. B-frag value at (col=l, k=m):
//   m=2n -> Ef2[(h*64+l)*32+n].x ; m=2n+1 -> .y   (kbase even, so n=(kbase+e)>>1)
__global__ void s4d_packE(const float2* __restrict__ Ef2,
                          short8* __restrict__ Ehi, short8* __restrict__ Elo) {
    int t = blockIdx.x * blockDim.x + threadIdx.x;
    if (t >= Hk * 512) return;
    int lane = t & 63, kh = (t >> 6) & 1, mt = (t >> 7) & 3, h = t >> 9;
    int col = mt * 16 + (lane & 15);
    int kbase = kh * 32 + ((lane >> 4) << 3);
    const float2* row = Ef2 + ((size_t)(h << 6) + col) * 32 + (kbase >> 1);
    short8 hi, lo;
    #pragma unroll
    for (int q = 0; q < 4; ++q) {
        float2 f = row[q];
        short a1, b1;
        split1(f.x, a1, b1); hi[2 * q] = a1;     lo[2 * q] = b1;
        split1(f.y, a1, b1); hi[2 * q + 1] = a1; lo[2 * q + 1] = b1;
    }
    Ehi[t] = hi; Elo[t] = lo;
}

// Fused main kernel — round-6 base with ONE change: carry moved from the
// readlane/VALU loop into phase-3 MFMA (S0 A-frags from linear LDS +
// E B-frags; 3-product bf16 split, same as the verified U*K path).
__global__ __launch_bounds__(256) void s4d_mm4(
    const float* __restrict__ u,
    const short8* __restrict__ Phi, const short8* __restrict__ Plo,
    const short8* __restrict__ Khi, const short8* __restrict__ Klo,
    const short8* __restrict__ Ehi, const short8* __restrict__ Elo,
    const float2* __restrict__ WS64, const float2* __restrict__ WS1024,
    float* __restrict__ y) {
    __shared__ __align__(16) float S[Gk * Tk];   // 32 KB
    __shared__ float Lb[NSEG * 64];              // 2 KB

    int b = blockIdx.x & (Bk - 1);
    int h = blockIdx.x >> 4;
    int bh = b * Hk + h;
    int tid = threadIdx.x;
    int lane = tid & 63, wv = tid >> 6;
    int lr = lane & 15, lq = lane >> 4;
    int cbase = wv * 32;
    const float* ub = u + (size_t)bh * Lk;

    // ---- U fragments: row c = cbase+ct*16+lr, k j = kh*32+lq*8+e
    short8 Uhi[2][2], Ulo[2][2];
    #pragma unroll
    for (int ct = 0; ct < 2; ++ct)
        #pragma unroll
        for (int kh = 0; kh < 2; ++kh) {
            const float* src = ub + (size_t)(cbase + ct * 16 + lr) * 64 + kh * 32 + lq * 8;
            float4 a4 = *(const float4*)src;
            float4 c4 = *(const float4*)(src + 4);
            float v[8] = {a4.x, a4.y, a4.z, a4.w, c4.x, c4.y, c4.z, c4.w};
            #pragma unroll
            for (int e = 0; e < 8; ++e) {
                short hi, lo; split1(v[e], hi, lo);
                Uhi[ct][kh][e] = hi; Ulo[ct][kh][e] = lo;
            }
        }

    // ---- phase 1: V -> S (linear) ----
    #pragma unroll
    for (int mt = 0; mt < 4; ++mt) {
        int tb = (((h << 2) + mt) << 1) * 64 + lane;
        short8 Bh0 = Phi[tb], Bl0 = Plo[tb];
        short8 Bh1 = Phi[tb + 64], Bl1 = Plo[tb + 64];
        #pragma unroll
        for (int ct = 0; ct < 2; ++ct) {
            f32x4 a = {0.f, 0.f, 0.f, 0.f};
            a = mfma16(Uhi[ct][0], Bh0, a);
            a = mfma16(Ulo[ct][0], Bh0, a);
            a = mfma16(Uhi[ct][0], Bl0, a);
            a = mfma16(Uhi[ct][1], Bh1, a);
            a = mfma16(Ulo[ct][1], Bh1, a);
            a = mfma16(Uhi[ct][1], Bl1, a);
            #pragma unroll
            for (int r = 0; r < 4; ++r)
                S[(cbase + ct * 16 + lq * 4 + r) * 64 + mt * 16 + lr] = a[r];
        }
    }
    __syncthreads();

    // ---- phase 2: segmented exclusive scan, thread = (mode n, segment g) ----
    {
        int n = tid & 31, g = tid >> 5;
        float2 W = WS64[(h << 5) + n];
        float zr = 0.f, zi = 0.f;
        for (int c = g * SEGC; c < g * SEGC + SEGC; ++c) {
            int a0 = c * 64 + 2 * n, a1 = a0 + 1;
            float vr = S[a0], vi = S[a1];
            S[a0] = zr; S[a1] = zi;
            float t_r = fmaf(W.x, zr, fmaf(-W.y, zi, vr));
            float t_i = fmaf(W.x, zi, fmaf(W.y, zr, vi));
            zr = t_r; zi = t_i;
        }
        Lb[g * 64 + 2 * n] = zr; Lb[g * 64 + 2 * n + 1] = zi;
        __syncthreads();
        if (tid < 32) {
            float2 Wseg = WS1024[(h << 5) + tid];
            float Zr = 0.f, Zi = 0.f;
            for (int g2 = 0; g2 < NSEG; ++g2) {
                float lr_ = Lb[g2 * 64 + 2 * tid], li_ = Lb[g2 * 64 + 2 * tid + 1];
                Lb[g2 * 64 + 2 * tid] = Zr; Lb[g2 * 64 + 2 * tid + 1] = Zi;
                float t_r = fmaf(Wseg.x, Zr, fmaf(-Wseg.y, Zi, lr_));
                float t_i = fmaf(Wseg.x, Zi, fmaf(Wseg.y, Zr, li_));
                Zr = t_r; Zi = t_i;
            }
        }
        __syncthreads();
        float pr = Lb[g * 64 + 2 * n], pi = Lb[g * 64 + 2 * n + 1];
        for (int c = g * SEGC; c < g * SEGC + SEGC; ++c) {
            int a0 = c * 64 + 2 * n, a1 = a0 + 1;
            S[a0] += pr; S[a1] += pi;
            float t_r = fmaf(W.x, pr, -W.y * pi);
            float t_i = fmaf(W.x, pi,  W.y * pr);
            pr = t_r; pi = t_i;
        }
    }
    __syncthreads();

    // ---- phase 3: y = U*K + S0*E (both MFMA) ----
    float* yb = y + (size_t)bh * Lk;
    #pragma unroll
    for (int ct = 0; ct < 2; ++ct) {
        // S0 A-fragments: row c = cbase+ct*16+lr, k m = kh*32+lq*8+e
        // (identical index pattern to the verified U-fragment load, from LDS)
        short8 Shi[2], Slo[2];
        #pragma unroll
        for (int kh = 0; kh < 2; ++kh) {
            const float* src = &S[(cbase + ct * 16 + lr) * 64 + kh * 32 + lq * 8];
            float4 g0 = *(const float4*)src;
            float4 g1 = *(const float4*)(src + 4);
            float v[8] = {g0.x, g0.y, g0.z, g0.w, g1.x, g1.y, g1.z, g1.w};
            #pragma unroll
            for (int e = 0; e < 8; ++e) {
                short hi, lo; split1(v[e], hi, lo);
                Shi[kh][e] = hi; Slo[kh][e] = lo;
            }
        }
        #pragma unroll
        for (int mt = 0; mt < 4; ++mt) {
            int tb = (((h << 2) + mt) << 1) * 64 + lane;
            short8 Kh0 = Khi[tb],      Kl0 = Klo[tb];
            short8 Kh1 = Khi[tb + 64], Kl1 = Klo[tb + 64];
            short8 Eh0 = Ehi[tb],      El0 = Elo[tb];
            short8 Eh1 = Ehi[tb + 64], El1 = Elo[tb + 64];
            f32x4 a = {0.f, 0.f, 0.f, 0.f};
            a = mfma16(Uhi[ct][0], Kh0, a);
            a = mfma16(Ulo[ct][0], Kh0, a);
            a = mfma16(Uhi[ct][0], Kl0, a);
            a = mfma16(Uhi[ct][1], Kh1, a);
            a = mfma16(Ulo[ct][1], Kh1, a);
            a = mfma16(Uhi[ct][1], Kl1, a);
            a = mfma16(Shi[0], Eh0, a);
            a = mfma16(Slo[0], Eh0, a);
            a = mfma16(Shi[0], El0, a);
            a = mfma16(Shi[1], Eh1, a);
            a = mfma16(Slo[1], Eh1, a);
            a = mfma16(Shi[1], El1, a);
            #pragma unroll
            for (int r = 0; r < 4; ++r) {
                int row = cbase + ct * 16 + lq * 4 + r;
                yb[(size_t)row * 64 + mt * 16 + lr] = a[r];
            }
        }
    }
}

extern "C" void kernel_launch(void* const* d_in, const int* in_sizes, int n_in,
                              void* d_out, int out_size, void* d_ws, size_t ws_size,
                              hipStream_t stream) {
    const float* u          = (const float*)d_in[0];
    const float* log_dt     = (const float*)d_in[1];
    const float* log_A_real = (const float*)d_in[2];
    const float* A_imag     = (const float*)d_in[3];
    const float* C          = (const float*)d_in[4];
    const float* D          = (const float*)d_in[5];
    float* y = (float*)d_out;

    char* ws = (char*)d_ws;
    double* MD     = (double*)(ws);
    float2* WS64   = (float2*)(ws + 262144);
    float2* WS1024 = (float2*)(ws + 327680);
    float*  kpart  = (float*) (ws + 393216);
    float*  kvec   = (float*) (ws + 655360);
    short*  Phi    = (short*) (ws + 720896);
    short*  Plo    = (short*) (ws + 2818048);
    short*  Khi    = (short*) (ws + 4915200);
    short*  Klo    = (short*) (ws + 7012352);
    float2* Ef2    = (float2*)(ws + 9109504);
    short*  Ehi    = (short*) (ws + 13303808);
    short*  Elo    = (short*) (ws + 15400960);

    s4d_p0<<<(Hk * N2k) / 256, 256, 0, stream>>>(log_dt, log_A_real, A_imag, C,
                                                 MD, WS64, WS1024);
    s4d_kvp<<<(Hk * 64 * 4) / 256, 256, 0, stream>>>(MD, kpart);
    s4d_kv2<<<(Hk * 64) / 256, 256, 0, stream>>>(kpart, D, kvec);
    s4d_packPK<<<(Hk * 512) / 256, 256, 0, stream>>>(MD, kvec,
                                                     (short8*)Phi, (short8*)Plo,
                                                     (short8*)Khi, (short8*)Klo);
    s4d_pe2<<<(Hk * 64 * 32) / 256, 256, 0, stream>>>(MD, Ef2);
    s4d_packE<<<(Hk * 512) / 256, 256, 0, stream>>>(Ef2, (short8*)Ehi, (short8*)Elo);
    s4d_mm4<<<Bk * Hk, 256, 0, stream>>>(u, (const short8*)Phi, (const short8*)Plo,
                                         (const short8*)Khi, (const short8*)Klo,
                                         (const short8*)Ehi, (const short8*)Elo,
                                         WS64, WS1024, y);
}